// Round 2
// 735.997 us; speedup vs baseline: 1.0119x; 1.0119x over previous
//
#include <hip/hip_runtime.h>
#include <hip/hip_fp16.h>

// Problem constants (S=3, Q=64, X=128, Y=128, Z=32, C=21)
#define NVOX 524288          // X*Y*Z voxels
#define NV4  131072          // NVOX/4 float4s per row
#define WPR  8192            // NVOX/64 bitmask words per query row
#define QN   64
#define SN   3
#define CN   21

typedef unsigned long long u64;
typedef float vfloat4 __attribute__((ext_vector_type(4)));  // native vec for nt-store

struct __align__(8) half4 { __half2 lo, hi; };

// Fast sigmoid for OUTPUT VALUES only (decisions are exact-integer popcounts).
// __expf + v_rcp: ~1e-7 rel err vs 1.9e-2 threshold.
__device__ __forceinline__ float fast_sigmoid(float x) {
    return __builtin_amdgcn_rcpf(1.0f + __expf(-x));
}

__device__ __forceinline__ void nt_store4(float4 v, float4* p) {
    vfloat4 nv = {v.x, v.y, v.z, v.w};
    __builtin_nontemporal_store(nv, (vfloat4*)p);
}

// ---------------------------------------------------------------------------
// K1: fused mask-build + row popcount for all S*Q rows. float4 loads.
// Bit mapping (permuted, consistent across ALL mask producers):
//   wave handles 64 consecutive float4 = 256 voxels = segment seg;
//   lane L holds voxels 4L..4L+3 as nibble bits j=0..3;
//   word seg*4+j = ballot(nibble bit j).
// Grid: 192 rows x 8 chunks = 1536 blocks of 256.
// ---------------------------------------------------------------------------
__global__ __launch_bounds__(256) void mask_rowsum_kernel(
    const float4* __restrict__ logits4, u64* __restrict__ B,
    unsigned int* __restrict__ part) {
    int r = blockIdx.x >> 3, c = blockIdx.x & 7;
    int tid = threadIdx.x, lane = tid & 63, wave = tid >> 6;
    const float4* row = logits4 + (size_t)r * NV4;
    int base = c * (NV4 / 8);          // 16384 float4 per chunk
    int pcnt = 0;
#pragma unroll 2
    for (int it = 0; it < 64; ++it) {
        int idx = base + it * 256 + tid;            // float4 index
        float4 v = row[idx];
        int nib = (v.x > 0.f ? 1 : 0) | (v.y > 0.f ? 2 : 0) |
                  (v.z > 0.f ? 4 : 0) | (v.w > 0.f ? 8 : 0);
        pcnt += __popc(nib);
        u64 b0 = __ballot(nib & 1);
        u64 b1 = __ballot(nib & 2);
        u64 b2 = __ballot(nib & 4);
        u64 b3 = __ballot(nib & 8);
        if (lane == 0) {
            int seg = idx >> 6;                     // wave-uniform
            ulonglong2* dst = (ulonglong2*)&B[(size_t)r * WPR + (size_t)seg * 4];
            dst[0] = make_ulonglong2(b0, b1);
            dst[1] = make_ulonglong2(b2, b3);
        }
    }
    for (int off = 32; off; off >>= 1) pcnt += __shfl_down(pcnt, off);
    __shared__ int red[4];
    if (lane == 0) red[wave] = pcnt;
    __syncthreads();
    if (tid == 0) part[blockIdx.x] = (unsigned)(red[0] + red[1] + red[2] + red[3]);
}

// ---------------------------------------------------------------------------
// K3: inter[q][p] = popcount(Ba[q] & Bb[p]), 4x4 tile/block, ulonglong2 loads.
// Grid: (16,16) blocks of 256.
// ---------------------------------------------------------------------------
__global__ __launch_bounds__(256) void inter_kernel(
    const u64* __restrict__ Ba, const u64* __restrict__ Bb,
    unsigned int* __restrict__ inter) {
    int q0 = blockIdx.y * 4, p0 = blockIdx.x * 4;
    int tid = threadIdx.x;
    const ulonglong2* A2 = (const ulonglong2*)Ba;
    const ulonglong2* B2 = (const ulonglong2*)Bb;
    int acc[4][4] = {};
    for (int w = tid; w < WPR / 2; w += 256) {
        ulonglong2 a[4], b[4];
#pragma unroll
        for (int i = 0; i < 4; ++i) a[i] = A2[(size_t)(q0 + i) * (WPR / 2) + w];
#pragma unroll
        for (int j = 0; j < 4; ++j) b[j] = B2[(size_t)(p0 + j) * (WPR / 2) + w];
#pragma unroll
        for (int i = 0; i < 4; ++i)
#pragma unroll
            for (int j = 0; j < 4; ++j)
                acc[i][j] += __popcll(a[i].x & b[j].x) + __popcll(a[i].y & b[j].y);
    }
    __shared__ int red[16][4];
    int lane = tid & 63, wave = tid >> 6;
#pragma unroll
    for (int i = 0; i < 4; ++i)
#pragma unroll
        for (int j = 0; j < 4; ++j) {
            int v = acc[i][j];
            for (int off = 32; off; off >>= 1) v += __shfl_down(v, off);
            if (lane == 0) red[i * 4 + j][wave] = v;
        }
    __syncthreads();
    if (tid < 16) {
        int s = red[tid][0] + red[tid][1] + red[tid][2] + red[tid][3];
        inter[(q0 + (tid >> 2)) * QN + (p0 + (tid & 3))] = (unsigned)s;
    }
}

// ---------------------------------------------------------------------------
// K4: per-anchor first-max argmax IoU + matched; stage2 also keep.
// pa: partial counts (8/row) for anchor rows; pa_alt/sel: stage2 fallback to
// original B0 counts for unmatched rows. Grid: 1 block of 64.
// ---------------------------------------------------------------------------
__global__ void finalize_kernel(
    const unsigned int* __restrict__ inter,
    const unsigned int* __restrict__ pa,
    const unsigned int* __restrict__ pa_alt, const int* __restrict__ sel,
    const unsigned int* __restrict__ pb,
    int* __restrict__ idx, int* __restrict__ matched, float* __restrict__ iou_out,
    int stage2, const float* __restrict__ iou_prev, float* __restrict__ keep) {
    __shared__ float nb[QN];
    int q = threadIdx.x;
    unsigned sb = 0;
#pragma unroll
    for (int k = 0; k < 8; ++k) sb += pb[q * 8 + k];
    nb[q] = (float)sb;
    __syncthreads();
    const unsigned int* pr = (sel && !sel[q]) ? pa_alt : pa;
    unsigned sa = 0;
#pragma unroll
    for (int k = 0; k < 8; ++k) sa += pr[q * 8 + k];
    float na = (float)sa;
    float best = -1.0f;
    int bidx = 0;
    for (int p = 0; p < QN; ++p) {
        float fi = (float)inter[q * QN + p];
        float un = fmaxf(na + nb[p] - fi, 1.0f);
        float iou = fi / un;                 // exact ints -> deterministic
        if (iou > best) { best = iou; bidx = p; }   // strict > = first max
    }
    idx[q] = bidx;
    iou_out[q] = best;
    matched[q] = (best > 0.2f) ? 1 : 0;
    if (stage2) keep[q] = (((iou_prev[q] + best) * 0.5f) > 0.2f) ? 1.0f : 0.0f;
}

// ---------------------------------------------------------------------------
// K5: merged anchor mask, IN PLACE over B0 (B0p aliases B0), PLUS fp16 cache
// of the merged pair-average value a01 = (sig(x0)+sig(x1))/2 (values only --
// decisions stay exact f32 sign tests / integer popcounts; fp16 err <=2^-12
// vs 1.9e-2 output threshold).
// matched: bit = (x0 + x1[idx]) > 0   [== (s0+s1)/2 > 0.5, sigmoid monotone]
// unmatched: B0 row already holds the correct bits -> early exit, no traffic;
//            a01 row left unwritten (final_kernel falls back to l0).
// Grid: 64 rows x 8 chunks = 512 blocks of 256.
// ---------------------------------------------------------------------------
__global__ __launch_bounds__(256) void mask2_kernel(
    const float4* __restrict__ logits4,
    const int* __restrict__ idx1, const int* __restrict__ m1,
    u64* __restrict__ B0p, unsigned int* __restrict__ partP,
    half4* __restrict__ a01w) {
    int q = blockIdx.x >> 3, c = blockIdx.x & 7;
    if (!m1[q]) return;                       // row keeps B0 bits + counts
    int tid = threadIdx.x, lane = tid & 63, wave = tid >> 6;
    const float4* r0 = logits4 + (size_t)q * NV4;
    const float4* r1 = logits4 + (size_t)(QN + idx1[q]) * NV4;
    int base = c * (NV4 / 8);
    int pcnt = 0;
#pragma unroll 2
    for (int it = 0; it < 64; ++it) {
        int idx = base + it * 256 + tid;
        float4 a = r0[idx];
        float4 b = r1[idx];
        int nib = (a.x + b.x > 0.f ? 1 : 0) | (a.y + b.y > 0.f ? 2 : 0) |
                  (a.z + b.z > 0.f ? 4 : 0) | (a.w + b.w > 0.f ? 8 : 0);
        pcnt += __popc(nib);
        // fp16 cache of merged VALUES (saves 268MB of re-reads in final)
        float v0 = (fast_sigmoid(a.x) + fast_sigmoid(b.x)) * 0.5f;
        float v1 = (fast_sigmoid(a.y) + fast_sigmoid(b.y)) * 0.5f;
        float v2 = (fast_sigmoid(a.z) + fast_sigmoid(b.z)) * 0.5f;
        float v3 = (fast_sigmoid(a.w) + fast_sigmoid(b.w)) * 0.5f;
        half4 h;
        h.lo = __floats2half2_rn(v0, v1);
        h.hi = __floats2half2_rn(v2, v3);
        a01w[(size_t)q * NV4 + idx] = h;
        u64 b0 = __ballot(nib & 1);
        u64 b1 = __ballot(nib & 2);
        u64 b2 = __ballot(nib & 4);
        u64 b3 = __ballot(nib & 8);
        if (lane == 0) {
            int seg = idx >> 6;
            ulonglong2* dst = (ulonglong2*)&B0p[(size_t)q * WPR + (size_t)seg * 4];
            dst[0] = make_ulonglong2(b0, b1);
            dst[1] = make_ulonglong2(b2, b3);
        }
    }
    for (int off = 32; off; off >>= 1) pcnt += __shfl_down(pcnt, off);
    __shared__ int red[4];
    if (lane == 0) red[wave] = pcnt;
    __syncthreads();
    if (tid == 0) partP[blockIdx.x] = (unsigned)(red[0] + red[1] + red[2] + red[3]);
}

// ---------------------------------------------------------------------------
// K6: final output with FUSED occupancy (occ_kernel deleted).
// Block = 128 float4 columns x all 64 q; threads 0..127 handle q 0..31 and
// also compute occ into LDS; threads 128..255 handle q 32..63.
// Matched rows read the 8B fp16 a01 cache instead of 32B of f32 logits.
// Per-q branches are block-uniform (no divergence). Output is write-once ->
// nontemporal store. Grid: 1024 blocks of 256 (4 blocks/CU).
// ---------------------------------------------------------------------------
__global__ __launch_bounds__(256) void final_kernel(
    const float4* __restrict__ logits4, const float4* __restrict__ sem4,
    const half4* __restrict__ a01,
    const int* __restrict__ m1_, const int* __restrict__ idx2_,
    const int* __restrict__ m2_, const float* __restrict__ keep_,
    float4* __restrict__ out4) {
    __shared__ int sm1[QN], sj2[QN], sm2[QN];
    __shared__ float sk[QN];
    __shared__ float4 sOcc[128];
    int tid = threadIdx.x;
    if (tid < QN) {
        sm1[tid] = m1_[tid]; sj2[tid] = idx2_[tid];
        sm2[tid] = m2_[tid]; sk[tid] = keep_[tid];
    }
    int colh = tid & 127, qh = tid >> 7;
    int n4 = blockIdx.x * 128 + colh;
    if (qh == 0) {   // waves 0,1: occ = (max_{c>=1} sem[c] > sem[0])
        float4 s0 = sem4[n4];
        float4 mx = sem4[NV4 + n4];
#pragma unroll
        for (int c = 2; c < CN; ++c) {
            float4 s = sem4[(size_t)c * NV4 + n4];
            mx.x = fmaxf(mx.x, s.x); mx.y = fmaxf(mx.y, s.y);
            mx.z = fmaxf(mx.z, s.z); mx.w = fmaxf(mx.w, s.w);
        }
        float4 o;
        o.x = (mx.x > s0.x) ? 1.f : 0.f; o.y = (mx.y > s0.y) ? 1.f : 0.f;
        o.z = (mx.z > s0.z) ? 1.f : 0.f; o.w = (mx.w > s0.w) ? 1.f : 0.f;
        sOcc[colh] = o;
    }
    __syncthreads();
    float4 oc = sOcc[colh];
#pragma unroll 4
    for (int qq = 0; qq < 32; ++qq) {
        int q = (qh << 5) + qq;
        float a0, a1, a2, a3;
        if (sm1[q]) {            // merged pair value from fp16 cache (8B)
            half4 h = a01[(size_t)q * NV4 + n4];
            float2 f0 = __half22float2(h.lo);
            float2 f1 = __half22float2(h.hi);
            a0 = f0.x; a1 = f0.y; a2 = f1.x; a3 = f1.y;
        } else {                 // unmatched: anchor value = sig(x0)
            float4 l0 = logits4[(size_t)q * NV4 + n4];
            a0 = fast_sigmoid(l0.x); a1 = fast_sigmoid(l0.y);
            a2 = fast_sigmoid(l0.z); a3 = fast_sigmoid(l0.w);
        }
        if (sm2[q]) {
            float4 l2 = logits4[(size_t)(2 * QN + sj2[q]) * NV4 + n4];
            const float t = 1.0f / 3.0f;
            a0 = (a0 * 2.f + fast_sigmoid(l2.x)) * t;
            a1 = (a1 * 2.f + fast_sigmoid(l2.y)) * t;
            a2 = (a2 * 2.f + fast_sigmoid(l2.z)) * t;
            a3 = (a3 * 2.f + fast_sigmoid(l2.w)) * t;
        }
        float kq = sk[q];
        float4 o;
        o.x = a0 * kq * oc.x; o.y = a1 * kq * oc.y;
        o.z = a2 * kq * oc.z; o.w = a3 * kq * oc.w;
        nt_store4(o, &out4[(size_t)q * NV4 + n4]);
    }
}

// ---------------------------------------------------------------------------
extern "C" void kernel_launch(void* const* d_in, const int* in_sizes, int n_in,
                              void* d_out, int out_size, void* d_ws, size_t ws_size,
                              hipStream_t stream) {
    const float4* vox4 = (const float4*)d_in[0];   // [3*64, 131072] float4
    const float4* sem4 = (const float4*)d_in[2];   // [21, 131072] float4
    float4* out4 = (float4*)d_out;
    (void)in_sizes; (void)n_in; (void)out_size; (void)ws_size; (void)d_in;

    // Workspace (~80 MB)
    char* p = (char*)d_ws;
    u64* Ball = (u64*)p;                            // 3 rowsets x 4 MB
    u64* B0 = Ball;                                 // B0p aliases B0 (in-place)
    u64* B1 = Ball + 1 * (size_t)QN * WPR;
    u64* B2 = Ball + 2 * (size_t)QN * WPR;
    char* p2 = p + 3ull * QN * WPR * 8;             // 12.58 MB
    half4* a01 = (half4*)p2;                        // 67 MB fp16 value cache
    char* p3 = p2 + (size_t)QN * NV4 * sizeof(half4);
    unsigned int* inter1 = (unsigned int*)p3;       // 4096
    unsigned int* inter2 = inter1 + QN * QN;
    unsigned int* partA  = inter2 + QN * QN;        // 192*8
    unsigned int* partP  = partA + 192 * 8;         // 64*8
    int* idx1 = (int*)(partP + 64 * 8);
    int* idx2 = idx1 + QN;
    int* m1   = idx2 + QN;
    int* m2   = m1 + QN;
    float* iou1 = (float*)(m2 + QN);
    float* iou2 = iou1 + QN;
    float* keep = iou2 + QN;

    // Stage 0: masks + row counts for all 3 subnets
    mask_rowsum_kernel<<<SN * QN * 8, 256, 0, stream>>>(vox4, Ball, partA);

    // Stage 1 matching: B0 vs B1
    inter_kernel<<<dim3(16, 16), 256, 0, stream>>>(B0, B1, inter1);
    finalize_kernel<<<1, 64, 0, stream>>>(inter1, partA, nullptr, nullptr,
                                          partA + QN * 8, idx1, m1, iou1,
                                          0, nullptr, nullptr);

    // Stage 2: merged anchor mask (in place over B0) + fp16 value cache,
    // then vs B2
    mask2_kernel<<<QN * 8, 256, 0, stream>>>(vox4, idx1, m1, B0, partP, a01);
    inter_kernel<<<dim3(16, 16), 256, 0, stream>>>(B0, B2, inter2);
    finalize_kernel<<<1, 64, 0, stream>>>(inter2, partP, partA, m1,
                                          partA + 2 * QN * 8, idx2, m2, iou2,
                                          1, iou1, keep);

    // Final output (occ fused)
    final_kernel<<<1024, 256, 0, stream>>>(
        vox4, sem4, a01, m1, idx2, m2, keep, out4);
}